// Round 8
// baseline (7810.537 us; speedup 1.0000x reference)
//
#include <hip/hip_runtime.h>

namespace {

constexpr int NB    = 256;
constexpr int NT    = 1024;
constexpr int NSTEP = NT - 1;
constexpr int D = 4, H = 64, W = 128;

typedef float v2f __attribute__((ext_vector_type(2)));

constexpr float cAT[6][5] = {
    {0.f, 0.f, 0.f, 0.f, 0.f},
    {0.161f, 0.f, 0.f, 0.f, 0.f},
    {-0.008480655492356989f, 0.335480655492357f, 0.f, 0.f, 0.f},
    {2.8971530571054935f, -6.359448489975075f, 4.3622954328695815f, 0.f, 0.f},
    {5.325864828439257f, -11.748883564062828f, 7.4955393428898365f, -0.09249506636175525f, 0.f},
    {5.86145544294642f, -12.92096931784711f, 8.159367898576159f, -0.071584973281401f, -0.028269050394068383f}};
constexpr float cFR[6] = {0.0f, 0.161f, 0.327f, 0.9f, 0.9800255409045097f, 1.0f};
constexpr float cBW[6] = {0.09646076681806523f, 0.01f, 0.4798896504144996f,
                          1.379008574103742f, -3.290069515436081f, 2.324710524099774f};

#define PINF(x) asm volatile("" : "+v"(x))

__device__ __forceinline__ float softplus_f(float x) {
    float e = __expf(-fabsf(x));
    return fmaxf(x, 0.0f) + __logf(1.0f + e);
}
__device__ __forceinline__ float tanh_f(float x) {
    float e = __expf(2.0f * x);
    return 1.0f - __fdividef(2.0f, 1.0f + e);
}

// DPP lane exchange. Patterns: 0xB1 xor1, 0x4E xor2 (quad_perm, involutions),
// 0x141 row_half_mirror (i<->7-i per 8, involution),
// 0x128 row_ror:8 (rot by 8 within 16 == lane^8 in BOTH directions -> direction-proof).
template <int CTRL>
__device__ __forceinline__ float dppmv(float x) {
    return __int_as_float(__builtin_amdgcn_mov_dpp(__float_as_int(x), CTRL, 0xF, 0xF, true));
}

// Padded LDS maps (16B-aligned chunks: pad 4 floats per 8 (h1) / per 16 (h2)).
__device__ __forceinline__ int p1m(int i) { return i + ((i >> 3) << 2); }  // s_h1: chunk8 +4
__device__ __forceinline__ int p2m(int i) { return i + ((i >> 4) << 2); }  // s_h2: chunk16 +4

// NOTE: grid is exactly 256 blocks = 1 block/CU. min-waves-per-EU = 2 (8 waves
// of one block / 4 SIMDs) -> 256-VGPR budget, weights truly register-resident.
__global__ __launch_bounds__(512, 2)
void cde_kernel_dummy(); // (placeholder to keep naming clear; real kernel below)

__global__ __launch_bounds__(512)
void cde_kernel(const float* __restrict__ ts,
                const float* __restrict__ coef_d,
                const float* __restrict__ coef_c,
                const float* __restrict__ coef_b,
                const float* __restrict__ coef_a,
                const float* __restrict__ W0, const float* __restrict__ b0,
                const float* __restrict__ W1, const float* __restrict__ b1,
                const float* __restrict__ W2, const float* __restrict__ b2,
                const float* __restrict__ F0, const float* __restrict__ g0,
                const float* __restrict__ F1, const float* __restrict__ g1,
                const float* __restrict__ F2, const float* __restrict__ g2,
                const float* __restrict__ Lm, const float* __restrict__ lb,
                float* __restrict__ out)
{
    const int b   = blockIdx.x;
    const int tid = threadIdx.x;

    const int q1 = tid & 15;    // L1/L2 input-slice id (16 per group)
    const int gO = tid >> 4;    // L1/L2 output group (32 groups x 4 outputs)
    const int q3 = tid & 7;     // L3 input-slice id (8 per group)
    const int g3 = tid >> 3;    // L3 group == h index (64) == RK state owner
    const bool wr12 = (q1 < 4);         // L1/L2 writer lanes (hold output gO*4+q1)
    const bool wry  = (q3 == 0);        // RK state writer
    const bool pb0  = (tid & 1) != 0;   // scatter parity bits
    const bool pb1  = (tid & 2) != 0;

    __shared__ __align__(16) float s_ys[64];
    __shared__ __align__(16) float s_h1[192];
    __shared__ __align__(16) float s_h2[160];

    // ---------------- persistent register-resident weights (float2 pairs) ----------------
    v2f wA2[8];    // F0[4gO+j][4q1 .. +3]
    v2f wB2[16];   // F1[4gO+j][8q1 .. +7]
    v2f wC2[32];   // F2[4g3+j][16q3 .. +15]
    #pragma unroll
    for (int j = 0; j < 4; ++j) {
        float4 v = *reinterpret_cast<const float4*>(F0 + (4*gO + j) * H + 4*q1);
        wA2[2*j]   = v2f{v.x, v.y};
        wA2[2*j+1] = v2f{v.z, v.w};
    }
    #pragma unroll
    for (int j = 0; j < 4; ++j)
        #pragma unroll
        for (int m = 0; m < 2; ++m) {
            float4 v = *reinterpret_cast<const float4*>(F1 + (4*gO + j) * W + 8*q1 + 4*m);
            wB2[4*j + 2*m]     = v2f{v.x, v.y};
            wB2[4*j + 2*m + 1] = v2f{v.z, v.w};
        }
    #pragma unroll
    for (int j = 0; j < 4; ++j)
        #pragma unroll
        for (int m = 0; m < 4; ++m) {
            float4 v = *reinterpret_cast<const float4*>(F2 + (4*g3 + j) * W + 16*q3 + 4*m);
            wC2[8*j + 2*m]     = v2f{v.x, v.y};
            wC2[8*j + 2*m + 1] = v2f{v.z, v.w};
        }
    float g0w = g0[4*gO + (tid & 3)];
    float g1w = g1[4*gO + (tid & 3)];
    float g2v0 = g2[4*g3 + 0], g2v1 = g2[4*g3 + 1], g2v2 = g2[4*g3 + 2], g2v3 = g2[4*g3 + 3];
    float L0r = Lm[0*H + (tid & 63)];
    float L1r = Lm[1*H + (tid & 63)];
    float L2r = Lm[2*H + (tid & 63)];
    const float lb0 = lb[0], lb1 = lb[1], lb2 = lb[2];

    #pragma unroll
    for (int i = 0; i < 8;  ++i) PINF(wA2[i]);
    #pragma unroll
    for (int i = 0; i < 16; ++i) PINF(wB2[i]);
    #pragma unroll
    for (int i = 0; i < 32; ++i) PINF(wC2[i]);
    PINF(g0w); PINF(g1w); PINF(g2v0); PINF(g2v1); PINF(g2v2); PINF(g2v3);
    PINF(L0r); PINF(L1r); PINF(L2r);

    // LDS pointers (all 16B-aligned bases, immediate offsets).
    const float* pA = s_ys + 4*q1;          // L1 act slice (1 float4)
    const float* pB = s_h1 + 12*q1;         // L2 act slice (2 float4)
    const float* pC = s_h2 + 20*q3;         // L3 act slice (4 float4)
    float* pw1 = s_h1 + p1m(4*gO + (tid & 3));
    float* pw2 = s_h2 + p2m(4*gO + (tid & 3));
    float* pwy = s_ys + g3;

    // fold + reduce-scatter over 16 lanes: returns output (tid&3)'s total.
    auto reduce16 = [&](float v0, float v1, float v2, float v3) -> float {
        v0 += dppmv<0x128>(v0); v1 += dppmv<0x128>(v1);
        v2 += dppmv<0x128>(v2); v3 += dppmv<0x128>(v3);
        v0 += dppmv<0x141>(v0); v1 += dppmv<0x141>(v1);
        v2 += dppmv<0x141>(v2); v3 += dppmv<0x141>(v3);
        float a  = pb0 ? v1 : v0;
        float as = pb0 ? v0 : v1;
        a += dppmv<0xB1>(as);
        float c  = pb0 ? v3 : v2;
        float cs = pb0 ? v2 : v3;
        c += dppmv<0xB1>(cs);
        float keep = pb1 ? c : a;
        float send = pb1 ? a : c;
        return keep + dppmv<0x4E>(send);
    };

    // ---------------- initial y0 = MLP(x0) ----------------
    if (tid < W) {
        const float4 x0 = *reinterpret_cast<const float4*>(coef_a + (size_t)b * NSTEP * D);
        const float4 w  = *reinterpret_cast<const float4*>(W0 + tid * D);
        s_h1[p1m(tid)] = softplus_f(w.x*x0.x + w.y*x0.y + w.z*x0.z + w.w*x0.w + b0[tid]);
    }
    __syncthreads();
    if (tid < W) {
        float a = b1[tid];
        #pragma unroll
        for (int c = 0; c < 16; ++c) {
            float4 wv0 = *reinterpret_cast<const float4*>(W1 + tid * W + 8*c);
            float4 wv1 = *reinterpret_cast<const float4*>(W1 + tid * W + 8*c + 4);
            float4 hv0 = *reinterpret_cast<const float4*>(s_h1 + 12*c);
            float4 hv1 = *reinterpret_cast<const float4*>(s_h1 + 12*c + 4);
            a += wv0.x*hv0.x + wv0.y*hv0.y + wv0.z*hv0.z + wv0.w*hv0.w
               + wv1.x*hv1.x + wv1.y*hv1.y + wv1.z*hv1.z + wv1.w*hv1.w;
        }
        s_h2[p2m(tid)] = softplus_f(a);
    }
    __syncthreads();
    if (tid < H) {
        float a = b2[tid];
        #pragma unroll
        for (int c = 0; c < 8; ++c)
            #pragma unroll
            for (int m = 0; m < 4; ++m) {
                float4 wv = *reinterpret_cast<const float4*>(W2 + tid * W + 16*c + 4*m);
                float4 hv = *reinterpret_cast<const float4*>(s_h2 + 20*c + 4*m);
                a += wv.x*hv.x + wv.y*hv.y + wv.z*hv.z + wv.w*hv.w;
            }
        s_ys[tid] = a;
    }
    __syncthreads();

    float y = *pwy;

    auto project = [&](int tslot) {
        if (tid < 64) {
            float yv = s_ys[tid];
            float p0 = yv * L0r, p1 = yv * L1r, p2 = yv * L2r;
            #pragma unroll
            for (int off = 32; off >= 1; off >>= 1) {
                p0 += __shfl_xor(p0, off);
                p1 += __shfl_xor(p1, off);
                p2 += __shfl_xor(p2, off);
            }
            if (tid == 0) {
                float* dst = out + ((size_t)b * NT + tslot) * 3;
                dst[0] = p0 + lb0; dst[1] = p1 + lb1; dst[2] = p2 + lb2;
            }
        }
    };
    project(0);

    const float* cb_p = coef_b + (size_t)b * NSTEP * D;
    const float* cc_p = coef_c + (size_t)b * NSTEP * D;
    const float* cd_p = coef_d + (size_t)b * NSTEP * D;

    // ---------------- main scan ----------------
    for (int t = 0; t < NSTEP; ++t) {
        const float4 cb4 = *reinterpret_cast<const float4*>(cb_p + (size_t)t * D);
        const float4 cc4 = *reinterpret_cast<const float4*>(cc_p + (size_t)t * D);
        const float4 cd4 = *reinterpret_cast<const float4*>(cd_p + (size_t)t * D);
        const float dtv = ts[t + 1] - ts[t];

        float k[6];

        #pragma unroll
        for (int s = 0; s < 6; ++s) {
            // ---- Phase A: L1 (64 -> 128), 4 outputs/thread, slice of 4 ----
            {
                float4 hv = *reinterpret_cast<const float4*>(pA);
                v2f h01 = v2f{hv.x, hv.y}, h23 = v2f{hv.z, hv.w};
                v2f a0 = __builtin_elementwise_fma(wA2[1], h23, wA2[0] * h01);
                v2f a1 = __builtin_elementwise_fma(wA2[3], h23, wA2[2] * h01);
                v2f a2 = __builtin_elementwise_fma(wA2[5], h23, wA2[4] * h01);
                v2f a3 = __builtin_elementwise_fma(wA2[7], h23, wA2[6] * h01);
                float c = reduce16(a0.x + a0.y, a1.x + a1.y, a2.x + a2.y, a3.x + a3.y);
                float sp = softplus_f(c + g0w);
                if (wr12) *pw1 = sp;
            }
            __syncthreads();

            // ---- Phase B: L2 (128 -> 128), 4 outputs/thread, slice of 8 ----
            {
                float4 u0 = *reinterpret_cast<const float4*>(pB);
                float4 u1 = *reinterpret_cast<const float4*>(pB + 4);
                v2f h0 = v2f{u0.x, u0.y}, h1 = v2f{u0.z, u0.w};
                v2f h2 = v2f{u1.x, u1.y}, h3 = v2f{u1.z, u1.w};
                v2f a0 = wB2[0]*h0, a1 = wB2[4]*h0, a2 = wB2[8]*h0, a3 = wB2[12]*h0;
                a0 = __builtin_elementwise_fma(wB2[1],  h1, a0);
                a1 = __builtin_elementwise_fma(wB2[5],  h1, a1);
                a2 = __builtin_elementwise_fma(wB2[9],  h1, a2);
                a3 = __builtin_elementwise_fma(wB2[13], h1, a3);
                a0 = __builtin_elementwise_fma(wB2[2],  h2, a0);
                a1 = __builtin_elementwise_fma(wB2[6],  h2, a1);
                a2 = __builtin_elementwise_fma(wB2[10], h2, a2);
                a3 = __builtin_elementwise_fma(wB2[14], h2, a3);
                a0 = __builtin_elementwise_fma(wB2[3],  h3, a0);
                a1 = __builtin_elementwise_fma(wB2[7],  h3, a1);
                a2 = __builtin_elementwise_fma(wB2[11], h3, a2);
                a3 = __builtin_elementwise_fma(wB2[15], h3, a3);
                float c = reduce16(a0.x + a0.y, a1.x + a1.y, a2.x + a2.y, a3.x + a3.y);
                float sp = softplus_f(c + g1w);
                if (wr12) *pw2 = sp;
            }
            __syncthreads();

            // ---- Phase C: L3 (128 -> 256) + einsum + RK, 4 outputs (= d 0..3 of h=g3) ----
            {
                v2f a0 = v2f{0.f, 0.f}, a1 = a0, a2 = a0, a3 = a0;
                #pragma unroll
                for (int m = 0; m < 4; ++m) {
                    float4 u = *reinterpret_cast<const float4*>(pC + 4*m);
                    v2f hlo = v2f{u.x, u.y}, hhi = v2f{u.z, u.w};
                    a0 = __builtin_elementwise_fma(wC2[2*m],      hlo, a0);
                    a0 = __builtin_elementwise_fma(wC2[2*m+1],    hhi, a0);
                    a1 = __builtin_elementwise_fma(wC2[8+2*m],    hlo, a1);
                    a1 = __builtin_elementwise_fma(wC2[8+2*m+1],  hhi, a1);
                    a2 = __builtin_elementwise_fma(wC2[16+2*m],   hlo, a2);
                    a2 = __builtin_elementwise_fma(wC2[16+2*m+1], hhi, a2);
                    a3 = __builtin_elementwise_fma(wC2[24+2*m],   hlo, a3);
                    a3 = __builtin_elementwise_fma(wC2[24+2*m+1], hhi, a3);
                }
                float v0 = a0.x + a0.y, v1 = a1.x + a1.y, v2 = a2.x + a2.y, v3 = a3.x + a3.y;
                // allreduce within the 8-lane group (xor1, xor2, then xor4 via half-mirror
                // -- valid because values are quad-uniform after xor1+xor2).
                v0 += dppmv<0xB1>(v0); v1 += dppmv<0xB1>(v1); v2 += dppmv<0xB1>(v2); v3 += dppmv<0xB1>(v3);
                v0 += dppmv<0x4E>(v0); v1 += dppmv<0x4E>(v1); v2 += dppmv<0x4E>(v2); v3 += dppmv<0x4E>(v3);
                v0 += dppmv<0x141>(v0); v1 += dppmv<0x141>(v1); v2 += dppmv<0x141>(v2); v3 += dppmv<0x141>(v3);

                const float f0 = tanh_f(v0 + g2v0);
                const float f1 = tanh_f(v1 + g2v1);
                const float f2 = tanh_f(v2 + g2v2);
                const float f3 = tanh_f(v3 + g2v3);

                const float frac = cFR[s] * dtv;
                const float dx0 = fmaf(frac, fmaf(3.0f*frac, cd4.x, 2.0f*cc4.x), cb4.x);
                const float dx1 = fmaf(frac, fmaf(3.0f*frac, cd4.y, 2.0f*cc4.y), cb4.y);
                const float dx2 = fmaf(frac, fmaf(3.0f*frac, cd4.z, 2.0f*cc4.z), cb4.z);
                const float dx3 = fmaf(frac, fmaf(3.0f*frac, cd4.w, 2.0f*cc4.w), cb4.w);
                k[s] = fmaf(f0, dx0, fmaf(f1, dx1, fmaf(f2, dx2, f3 * dx3)));

                float ysn;
                if (s < 5) {
                    float acc = 0.f;
                    #pragma unroll
                    for (int i = 0; i <= s; ++i) acc = fmaf(cAT[s+1][i], k[i], acc);
                    ysn = fmaf(dtv, acc, y);
                } else {
                    float acc = 0.f;
                    #pragma unroll
                    for (int i = 0; i < 6; ++i) acc = fmaf(cBW[i], k[i], acc);
                    ysn = fmaf(dtv, acc, y);
                }
                if (wry) *pwy = ysn;
            }
            __syncthreads();
        }

        y = *pwy;          // single source of truth: writer lane's value
        project(t + 1);    // wave0 overlaps with other waves' next phase A
    }
}

} // namespace

extern "C" void kernel_launch(void* const* d_in, const int* in_sizes, int n_in,
                              void* d_out, int out_size, void* d_ws, size_t ws_size,
                              hipStream_t stream) {
    const float* ts     = (const float*)d_in[0];
    const float* coef_d = (const float*)d_in[1];
    const float* coef_c = (const float*)d_in[2];
    const float* coef_b = (const float*)d_in[3];
    const float* coef_a = (const float*)d_in[4];
    const float* W0 = (const float*)d_in[5];
    const float* b0 = (const float*)d_in[6];
    const float* W1 = (const float*)d_in[7];
    const float* b1 = (const float*)d_in[8];
    const float* W2 = (const float*)d_in[9];
    const float* b2 = (const float*)d_in[10];
    const float* F0 = (const float*)d_in[11];
    const float* g0 = (const float*)d_in[12];
    const float* F1 = (const float*)d_in[13];
    const float* g1 = (const float*)d_in[14];
    const float* F2 = (const float*)d_in[15];
    const float* g2 = (const float*)d_in[16];
    const float* Lm = (const float*)d_in[17];
    const float* lb = (const float*)d_in[18];
    float* out = (float*)d_out;

    hipLaunchKernelGGL(cde_kernel, dim3(NB), dim3(512), 0, stream,
                       ts, coef_d, coef_c, coef_b, coef_a,
                       W0, b0, W1, b1, W2, b2,
                       F0, g0, F1, g1, F2, g2, Lm, lb, out);
}

// Round 10
// 7778.888 us; speedup vs baseline: 1.0041x; 1.0041x over previous
//
#include <hip/hip_runtime.h>

namespace {

constexpr int NB    = 256;
constexpr int NT    = 1024;
constexpr int NSTEP = NT - 1;
constexpr int D = 4, H = 64, W = 128;

typedef float v2f __attribute__((ext_vector_type(2)));

constexpr float cAT[6][5] = {
    {0.f, 0.f, 0.f, 0.f, 0.f},
    {0.161f, 0.f, 0.f, 0.f, 0.f},
    {-0.008480655492356989f, 0.335480655492357f, 0.f, 0.f, 0.f},
    {2.8971530571054935f, -6.359448489975075f, 4.3622954328695815f, 0.f, 0.f},
    {5.325864828439257f, -11.748883564062828f, 7.4955393428898365f, -0.09249506636175525f, 0.f},
    {5.86145544294642f, -12.92096931784711f, 8.159367898576159f, -0.071584973281401f, -0.028269050394068383f}};
constexpr float cFR[6] = {0.0f, 0.161f, 0.327f, 0.9f, 0.9800255409045097f, 1.0f};
constexpr float cBW[6] = {0.09646076681806523f, 0.01f, 0.4798896504144996f,
                          1.379008574103742f, -3.290069515436081f, 2.324710524099774f};

#define PINF(x) asm volatile("" : "+v"(x))

__device__ __forceinline__ float softplus_f(float x) {
    float e = __expf(-fabsf(x));
    return fmaxf(x, 0.0f) + __logf(1.0f + e);
}
__device__ __forceinline__ float tanh_f(float x) {
    float e = __expf(2.0f * x);
    return 1.0f - __fdividef(2.0f, 1.0f + e);
}

// DPP lane exchange. Patterns: 0xB1 xor1, 0x4E xor2 (quad_perm, involutions),
// 0x141 row_half_mirror (i<->7-i per 8, involution),
// 0x128 row_ror:8 (rot by 8 within 16 == lane^8 in BOTH directions -> direction-proof).
template <int CTRL>
__device__ __forceinline__ float dppmv(float x) {
    return __int_as_float(__builtin_amdgcn_mov_dpp(__float_as_int(x), CTRL, 0xF, 0xF, true));
}

// Padded LDS maps (16B-aligned chunks: pad 4 floats per 8 (h1) / per 16 (h2)).
__device__ __forceinline__ int p1m(int i) { return i + ((i >> 3) << 2); }  // s_h1: chunk8 +4
__device__ __forceinline__ int p2m(int i) { return i + ((i >> 4) << 2); }  // s_h2: chunk16 +4

// Grid is exactly 256 blocks = 1 block/CU = 8 waves/CU = 2 waves/EU, fixed by
// the problem (B=256). amdgpu_waves_per_eu(2,2) tells the allocator occupancy
// is pinned at 2 waves/EU -> full 256-VGPR budget, no AGPR-spill of weights.
__global__ __launch_bounds__(512) __attribute__((amdgpu_waves_per_eu(2, 2)))
void cde_kernel(const float* __restrict__ ts,
                const float* __restrict__ coef_d,
                const float* __restrict__ coef_c,
                const float* __restrict__ coef_b,
                const float* __restrict__ coef_a,
                const float* __restrict__ W0, const float* __restrict__ b0,
                const float* __restrict__ W1, const float* __restrict__ b1,
                const float* __restrict__ W2, const float* __restrict__ b2,
                const float* __restrict__ F0, const float* __restrict__ g0,
                const float* __restrict__ F1, const float* __restrict__ g1,
                const float* __restrict__ F2, const float* __restrict__ g2,
                const float* __restrict__ Lm, const float* __restrict__ lb,
                float* __restrict__ out)
{
    const int b   = blockIdx.x;
    const int tid = threadIdx.x;

    const int q1 = tid & 15;    // L1/L2 input-slice id (16 per group)
    const int gO = tid >> 4;    // L1/L2 output group (32 groups x 4 outputs)
    const int q3 = tid & 7;     // L3 input-slice id (8 per group)
    const int g3 = tid >> 3;    // L3 group == h index (64) == RK state owner
    const bool wr12 = (q1 < 4);         // L1/L2 writer lanes (hold output gO*4+q1)
    const bool wry  = (q3 == 0);        // RK state writer
    const bool pb0  = (tid & 1) != 0;   // scatter parity bits
    const bool pb1  = (tid & 2) != 0;

    __shared__ __align__(16) float s_ys[64];
    __shared__ __align__(16) float s_h1[192];
    __shared__ __align__(16) float s_h2[160];

    // ---------------- persistent register-resident weights (float2 pairs) ----------------
    v2f wA2[8];    // F0[4gO+j][4q1 .. +3]
    v2f wB2[16];   // F1[4gO+j][8q1 .. +7]
    v2f wC2[32];   // F2[4g3+j][16q3 .. +15]
    #pragma unroll
    for (int j = 0; j < 4; ++j) {
        float4 v = *reinterpret_cast<const float4*>(F0 + (4*gO + j) * H + 4*q1);
        wA2[2*j]   = v2f{v.x, v.y};
        wA2[2*j+1] = v2f{v.z, v.w};
    }
    #pragma unroll
    for (int j = 0; j < 4; ++j)
        #pragma unroll
        for (int m = 0; m < 2; ++m) {
            float4 v = *reinterpret_cast<const float4*>(F1 + (4*gO + j) * W + 8*q1 + 4*m);
            wB2[4*j + 2*m]     = v2f{v.x, v.y};
            wB2[4*j + 2*m + 1] = v2f{v.z, v.w};
        }
    #pragma unroll
    for (int j = 0; j < 4; ++j)
        #pragma unroll
        for (int m = 0; m < 4; ++m) {
            float4 v = *reinterpret_cast<const float4*>(F2 + (4*g3 + j) * W + 16*q3 + 4*m);
            wC2[8*j + 2*m]     = v2f{v.x, v.y};
            wC2[8*j + 2*m + 1] = v2f{v.z, v.w};
        }
    float g0w = g0[4*gO + (tid & 3)];
    float g1w = g1[4*gO + (tid & 3)];
    float g2v0 = g2[4*g3 + 0], g2v1 = g2[4*g3 + 1], g2v2 = g2[4*g3 + 2], g2v3 = g2[4*g3 + 3];
    float L0r = Lm[0*H + (tid & 63)];
    float L1r = Lm[1*H + (tid & 63)];
    float L2r = Lm[2*H + (tid & 63)];
    const float lb0 = lb[0], lb1 = lb[1], lb2 = lb[2];

    #pragma unroll
    for (int i = 0; i < 8;  ++i) PINF(wA2[i]);
    #pragma unroll
    for (int i = 0; i < 16; ++i) PINF(wB2[i]);
    #pragma unroll
    for (int i = 0; i < 32; ++i) PINF(wC2[i]);
    PINF(g0w); PINF(g1w); PINF(g2v0); PINF(g2v1); PINF(g2v2); PINF(g2v3);
    PINF(L0r); PINF(L1r); PINF(L2r);

    // LDS pointers (all 16B-aligned bases, immediate offsets).
    const float* pA = s_ys + 4*q1;          // L1 act slice (1 float4)
    const float* pB = s_h1 + 12*q1;         // L2 act slice (2 float4)
    const float* pC = s_h2 + 20*q3;         // L3 act slice (4 float4)
    float* pw1 = s_h1 + p1m(4*gO + (tid & 3));
    float* pw2 = s_h2 + p2m(4*gO + (tid & 3));
    float* pwy = s_ys + g3;

    // fold + reduce-scatter over 16 lanes: returns output (tid&3)'s total.
    auto reduce16 = [&](float v0, float v1, float v2, float v3) -> float {
        v0 += dppmv<0x128>(v0); v1 += dppmv<0x128>(v1);
        v2 += dppmv<0x128>(v2); v3 += dppmv<0x128>(v3);
        v0 += dppmv<0x141>(v0); v1 += dppmv<0x141>(v1);
        v2 += dppmv<0x141>(v2); v3 += dppmv<0x141>(v3);
        float a  = pb0 ? v1 : v0;
        float as = pb0 ? v0 : v1;
        a += dppmv<0xB1>(as);
        float c  = pb0 ? v3 : v2;
        float cs = pb0 ? v2 : v3;
        c += dppmv<0xB1>(cs);
        float keep = pb1 ? c : a;
        float send = pb1 ? a : c;
        return keep + dppmv<0x4E>(send);
    };

    // ---------------- initial y0 = MLP(x0) ----------------
    if (tid < W) {
        const float4 x0 = *reinterpret_cast<const float4*>(coef_a + (size_t)b * NSTEP * D);
        const float4 w  = *reinterpret_cast<const float4*>(W0 + tid * D);
        s_h1[p1m(tid)] = softplus_f(w.x*x0.x + w.y*x0.y + w.z*x0.z + w.w*x0.w + b0[tid]);
    }
    __syncthreads();
    if (tid < W) {
        float a = b1[tid];
        #pragma unroll
        for (int c = 0; c < 16; ++c) {
            float4 wv0 = *reinterpret_cast<const float4*>(W1 + tid * W + 8*c);
            float4 wv1 = *reinterpret_cast<const float4*>(W1 + tid * W + 8*c + 4);
            float4 hv0 = *reinterpret_cast<const float4*>(s_h1 + 12*c);
            float4 hv1 = *reinterpret_cast<const float4*>(s_h1 + 12*c + 4);
            a += wv0.x*hv0.x + wv0.y*hv0.y + wv0.z*hv0.z + wv0.w*hv0.w
               + wv1.x*hv1.x + wv1.y*hv1.y + wv1.z*hv1.z + wv1.w*hv1.w;
        }
        s_h2[p2m(tid)] = softplus_f(a);
    }
    __syncthreads();
    if (tid < H) {
        float a = b2[tid];
        #pragma unroll
        for (int c = 0; c < 8; ++c)
            #pragma unroll
            for (int m = 0; m < 4; ++m) {
                float4 wv = *reinterpret_cast<const float4*>(W2 + tid * W + 16*c + 4*m);
                float4 hv = *reinterpret_cast<const float4*>(s_h2 + 20*c + 4*m);
                a += wv.x*hv.x + wv.y*hv.y + wv.z*hv.z + wv.w*hv.w;
            }
        s_ys[tid] = a;
    }
    __syncthreads();

    float y = *pwy;

    auto project = [&](int tslot) {
        if (tid < 64) {
            float yv = s_ys[tid];
            float p0 = yv * L0r, p1 = yv * L1r, p2 = yv * L2r;
            #pragma unroll
            for (int off = 32; off >= 1; off >>= 1) {
                p0 += __shfl_xor(p0, off);
                p1 += __shfl_xor(p1, off);
                p2 += __shfl_xor(p2, off);
            }
            if (tid == 0) {
                float* dst = out + ((size_t)b * NT + tslot) * 3;
                dst[0] = p0 + lb0; dst[1] = p1 + lb1; dst[2] = p2 + lb2;
            }
        }
    };
    project(0);

    const float* cb_p = coef_b + (size_t)b * NSTEP * D;
    const float* cc_p = coef_c + (size_t)b * NSTEP * D;
    const float* cd_p = coef_d + (size_t)b * NSTEP * D;

    // ---------------- main scan ----------------
    for (int t = 0; t < NSTEP; ++t) {
        const float4 cb4 = *reinterpret_cast<const float4*>(cb_p + (size_t)t * D);
        const float4 cc4 = *reinterpret_cast<const float4*>(cc_p + (size_t)t * D);
        const float4 cd4 = *reinterpret_cast<const float4*>(cd_p + (size_t)t * D);
        const float dtv = ts[t + 1] - ts[t];

        float k[6];

        #pragma unroll
        for (int s = 0; s < 6; ++s) {
            // ---- Phase A: L1 (64 -> 128), 4 outputs/thread, slice of 4 ----
            {
                float4 hv = *reinterpret_cast<const float4*>(pA);
                v2f h01 = v2f{hv.x, hv.y}, h23 = v2f{hv.z, hv.w};
                v2f a0 = __builtin_elementwise_fma(wA2[1], h23, wA2[0] * h01);
                v2f a1 = __builtin_elementwise_fma(wA2[3], h23, wA2[2] * h01);
                v2f a2 = __builtin_elementwise_fma(wA2[5], h23, wA2[4] * h01);
                v2f a3 = __builtin_elementwise_fma(wA2[7], h23, wA2[6] * h01);
                float c = reduce16(a0.x + a0.y, a1.x + a1.y, a2.x + a2.y, a3.x + a3.y);
                float sp = softplus_f(c + g0w);
                if (wr12) *pw1 = sp;
            }
            __syncthreads();

            // ---- Phase B: L2 (128 -> 128), 4 outputs/thread, slice of 8 ----
            {
                float4 u0 = *reinterpret_cast<const float4*>(pB);
                float4 u1 = *reinterpret_cast<const float4*>(pB + 4);
                v2f h0 = v2f{u0.x, u0.y}, h1 = v2f{u0.z, u0.w};
                v2f h2 = v2f{u1.x, u1.y}, h3 = v2f{u1.z, u1.w};
                v2f a0 = wB2[0]*h0, a1 = wB2[4]*h0, a2 = wB2[8]*h0, a3 = wB2[12]*h0;
                a0 = __builtin_elementwise_fma(wB2[1],  h1, a0);
                a1 = __builtin_elementwise_fma(wB2[5],  h1, a1);
                a2 = __builtin_elementwise_fma(wB2[9],  h1, a2);
                a3 = __builtin_elementwise_fma(wB2[13], h1, a3);
                a0 = __builtin_elementwise_fma(wB2[2],  h2, a0);
                a1 = __builtin_elementwise_fma(wB2[6],  h2, a1);
                a2 = __builtin_elementwise_fma(wB2[10], h2, a2);
                a3 = __builtin_elementwise_fma(wB2[14], h2, a3);
                a0 = __builtin_elementwise_fma(wB2[3],  h3, a0);
                a1 = __builtin_elementwise_fma(wB2[7],  h3, a1);
                a2 = __builtin_elementwise_fma(wB2[11], h3, a2);
                a3 = __builtin_elementwise_fma(wB2[15], h3, a3);
                float c = reduce16(a0.x + a0.y, a1.x + a1.y, a2.x + a2.y, a3.x + a3.y);
                float sp = softplus_f(c + g1w);
                if (wr12) *pw2 = sp;
            }
            __syncthreads();

            // ---- Phase C: L3 (128 -> 256) + einsum + RK, 4 outputs (= d 0..3 of h=g3) ----
            {
                v2f a0 = v2f{0.f, 0.f}, a1 = a0, a2 = a0, a3 = a0;
                #pragma unroll
                for (int m = 0; m < 4; ++m) {
                    float4 u = *reinterpret_cast<const float4*>(pC + 4*m);
                    v2f hlo = v2f{u.x, u.y}, hhi = v2f{u.z, u.w};
                    a0 = __builtin_elementwise_fma(wC2[2*m],      hlo, a0);
                    a0 = __builtin_elementwise_fma(wC2[2*m+1],    hhi, a0);
                    a1 = __builtin_elementwise_fma(wC2[8+2*m],    hlo, a1);
                    a1 = __builtin_elementwise_fma(wC2[8+2*m+1],  hhi, a1);
                    a2 = __builtin_elementwise_fma(wC2[16+2*m],   hlo, a2);
                    a2 = __builtin_elementwise_fma(wC2[16+2*m+1], hhi, a2);
                    a3 = __builtin_elementwise_fma(wC2[24+2*m],   hlo, a3);
                    a3 = __builtin_elementwise_fma(wC2[24+2*m+1], hhi, a3);
                }
                float v0 = a0.x + a0.y, v1 = a1.x + a1.y, v2 = a2.x + a2.y, v3 = a3.x + a3.y;
                // allreduce within the 8-lane group (xor1, xor2, then xor4 via half-mirror
                // -- valid because values are quad-uniform after xor1+xor2).
                v0 += dppmv<0xB1>(v0); v1 += dppmv<0xB1>(v1); v2 += dppmv<0xB1>(v2); v3 += dppmv<0xB1>(v3);
                v0 += dppmv<0x4E>(v0); v1 += dppmv<0x4E>(v1); v2 += dppmv<0x4E>(v2); v3 += dppmv<0x4E>(v3);
                v0 += dppmv<0x141>(v0); v1 += dppmv<0x141>(v1); v2 += dppmv<0x141>(v2); v3 += dppmv<0x141>(v3);

                const float f0 = tanh_f(v0 + g2v0);
                const float f1 = tanh_f(v1 + g2v1);
                const float f2 = tanh_f(v2 + g2v2);
                const float f3 = tanh_f(v3 + g2v3);

                const float frac = cFR[s] * dtv;
                const float dx0 = fmaf(frac, fmaf(3.0f*frac, cd4.x, 2.0f*cc4.x), cb4.x);
                const float dx1 = fmaf(frac, fmaf(3.0f*frac, cd4.y, 2.0f*cc4.y), cb4.y);
                const float dx2 = fmaf(frac, fmaf(3.0f*frac, cd4.z, 2.0f*cc4.z), cb4.z);
                const float dx3 = fmaf(frac, fmaf(3.0f*frac, cd4.w, 2.0f*cc4.w), cb4.w);
                k[s] = fmaf(f0, dx0, fmaf(f1, dx1, fmaf(f2, dx2, f3 * dx3)));

                float ysn;
                if (s < 5) {
                    float acc = 0.f;
                    #pragma unroll
                    for (int i = 0; i <= s; ++i) acc = fmaf(cAT[s+1][i], k[i], acc);
                    ysn = fmaf(dtv, acc, y);
                } else {
                    float acc = 0.f;
                    #pragma unroll
                    for (int i = 0; i < 6; ++i) acc = fmaf(cBW[i], k[i], acc);
                    ysn = fmaf(dtv, acc, y);
                }
                if (wry) *pwy = ysn;
            }
            __syncthreads();
        }

        y = *pwy;          // single source of truth: writer lane's value
        project(t + 1);    // wave0 overlaps with other waves' next phase A
    }
}

} // namespace

extern "C" void kernel_launch(void* const* d_in, const int* in_sizes, int n_in,
                              void* d_out, int out_size, void* d_ws, size_t ws_size,
                              hipStream_t stream) {
    const float* ts     = (const float*)d_in[0];
    const float* coef_d = (const float*)d_in[1];
    const float* coef_c = (const float*)d_in[2];
    const float* coef_b = (const float*)d_in[3];
    const float* coef_a = (const float*)d_in[4];
    const float* W0 = (const float*)d_in[5];
    const float* b0 = (const float*)d_in[6];
    const float* W1 = (const float*)d_in[7];
    const float* b1 = (const float*)d_in[8];
    const float* W2 = (const float*)d_in[9];
    const float* b2 = (const float*)d_in[10];
    const float* F0 = (const float*)d_in[11];
    const float* g0 = (const float*)d_in[12];
    const float* F1 = (const float*)d_in[13];
    const float* g1 = (const float*)d_in[14];
    const float* F2 = (const float*)d_in[15];
    const float* g2 = (const float*)d_in[16];
    const float* Lm = (const float*)d_in[17];
    const float* lb = (const float*)d_in[18];
    float* out = (float*)d_out;

    hipLaunchKernelGGL(cde_kernel, dim3(NB), dim3(512), 0, stream,
                       ts, coef_d, coef_c, coef_b, coef_a,
                       W0, b0, W1, b1, W2, b2,
                       F0, g0, F1, g1, F2, g2, Lm, lb, out);
}

// Round 11
// 6207.684 us; speedup vs baseline: 1.2582x; 1.2531x over previous
//
#include <hip/hip_runtime.h>

namespace {

constexpr int NB    = 256;
constexpr int NT    = 1024;
constexpr int NSTEP = NT - 1;
constexpr int D = 4, H = 64, W = 128;

constexpr float cAT[6][5] = {
    {0.f, 0.f, 0.f, 0.f, 0.f},
    {0.161f, 0.f, 0.f, 0.f, 0.f},
    {-0.008480655492356989f, 0.335480655492357f, 0.f, 0.f, 0.f},
    {2.8971530571054935f, -6.359448489975075f, 4.3622954328695815f, 0.f, 0.f},
    {5.325864828439257f, -11.748883564062828f, 7.4955393428898365f, -0.09249506636175525f, 0.f},
    {5.86145544294642f, -12.92096931784711f, 8.159367898576159f, -0.071584973281401f, -0.028269050394068383f}};
constexpr float cFR[6] = {0.0f, 0.161f, 0.327f, 0.9f, 0.9800255409045097f, 1.0f};
constexpr float cBW[6] = {0.09646076681806523f, 0.01f, 0.4798896504144996f,
                          1.379008574103742f, -3.290069515436081f, 2.324710524099774f};

__device__ __forceinline__ float softplus_f(float x) {
    float e = __expf(-fabsf(x));
    return fmaxf(x, 0.0f) + __logf(1.0f + e);
}
__device__ __forceinline__ float tanh_f(float x) {
    float e = __expf(2.0f * x);
    return 1.0f - __fdividef(2.0f, 1.0f + e);
}

// HW-validated DPP involutions only:
// 0xB1 quad_perm xor1 | 0x4E quad_perm xor2 | 0x141 row_half_mirror (i<->7-i per 8)
template <int CTRL>
__device__ __forceinline__ float dppmv(float x) {
    return __int_as_float(__builtin_amdgcn_mov_dpp(__float_as_int(x), CTRL, 0xF, 0xF, true));
}

// Padded LDS index maps (16B-aligned chunk bases):
__device__ __forceinline__ int pY(int i)  { return (i >> 4) * 20 + (i & 15); }  // s_ys : 4x20
__device__ __forceinline__ int p1i(int i) { return (i >> 5) * 36 + (i & 31); }  // s_h1 : 4x36
__device__ __forceinline__ int p2i(int i) { return (i >> 6) * 72 + (i & 63); }  // s_h2 : 2x72

__global__ __launch_bounds__(512, 2)
void cde_kernel(const float* __restrict__ ts,
                const float* __restrict__ coef_d,
                const float* __restrict__ coef_c,
                const float* __restrict__ coef_b,
                const float* __restrict__ coef_a,
                const float* __restrict__ W0, const float* __restrict__ b0,
                const float* __restrict__ W1, const float* __restrict__ b1,
                const float* __restrict__ W2, const float* __restrict__ b2,
                const float* __restrict__ F0, const float* __restrict__ g0,
                const float* __restrict__ F1, const float* __restrict__ g1,
                const float* __restrict__ F2, const float* __restrict__ g2,
                const float* __restrict__ Lm, const float* __restrict__ lb,
                float* __restrict__ out)
{
    const int b    = blockIdx.x;
    const int tid  = threadIdx.x;

    const int j12  = tid >> 2;   // A: output index (128), quad-sliced
    const int q12  = tid & 3;
    const int og   = tid >> 3;   // B: output-pair group (64) -> outputs {2og, 2og+1}
    const int q2   = tid & 7;    //    16-float slice id
    const int grp  = tid >> 2;   // C: output-pair quad (128) -> outputs {2grp, 2grp+1}
    const int qc   = tid & 3;    //    32-float slice id
    const int g3   = tid >> 3;   // RK state owner (== og)
    const int dsel = ((tid >> 2) & 1) * 2 + (tid & 1);   // d of output 2grp+(tid&1)

    __shared__ __align__(16) float s_ys[80];
    __shared__ __align__(16) float s_h1[144];
    __shared__ __align__(16) float s_h2[136];

    // ---------------- persistent weights (R6 scalar style, no pins) ----------------
    float wA[16];                 // F0[j12][16q12 .. +15]
    float wB0[16], wB1[16];       // F1[2og(+1)][16q2 .. +15]
    float wC0[32], wC1[32];       // F2[2grp(+1)][32qc .. +31]
    #pragma unroll
    for (int i = 0; i < 16; i += 4) {
        float4 v = *reinterpret_cast<const float4*>(F0 + j12 * H + q12 * 16 + i);
        wA[i+0]=v.x; wA[i+1]=v.y; wA[i+2]=v.z; wA[i+3]=v.w;
    }
    #pragma unroll
    for (int i = 0; i < 16; i += 4) {
        float4 v0 = *reinterpret_cast<const float4*>(F1 + (2*og)     * W + q2 * 16 + i);
        float4 v1 = *reinterpret_cast<const float4*>(F1 + (2*og + 1) * W + q2 * 16 + i);
        wB0[i+0]=v0.x; wB0[i+1]=v0.y; wB0[i+2]=v0.z; wB0[i+3]=v0.w;
        wB1[i+0]=v1.x; wB1[i+1]=v1.y; wB1[i+2]=v1.z; wB1[i+3]=v1.w;
    }
    #pragma unroll
    for (int i = 0; i < 32; i += 4) {
        float4 v0 = *reinterpret_cast<const float4*>(F2 + (2*grp)     * W + qc * 32 + i);
        float4 v1 = *reinterpret_cast<const float4*>(F2 + (2*grp + 1) * W + qc * 32 + i);
        wC0[i+0]=v0.x; wC0[i+1]=v0.y; wC0[i+2]=v0.z; wC0[i+3]=v0.w;
        wC1[i+0]=v1.x; wC1[i+1]=v1.y; wC1[i+2]=v1.z; wC1[i+3]=v1.w;
    }
    const float g0r = g0[j12];
    const float g1s = g1[2*og  + (q2  & 1)];
    const float g2s = g2[2*grp + (tid & 1)];
    const float L0r = Lm[0*H + (tid & 63)];
    const float L1r = Lm[1*H + (tid & 63)];
    const float L2r = Lm[2*H + (tid & 63)];
    const float lb0 = lb[0], lb1 = lb[1], lb2 = lb[2];

    // LDS pointers (16B-aligned bases, immediate offsets).
    const float* pA = s_ys + q12 * 20;                         // 4 float4
    const float* pB = s_h1 + (q2 >> 1) * 36 + (q2 & 1) * 16;   // 4 float4 (slice [16q2,+16))
    const float* pC = s_h2 + (qc >> 1) * 72 + (qc & 1) * 32;   // 8 float4 (slice [32qc,+32))
    float* pw1 = s_h1 + p1i(j12);
    float* pw2 = s_h2 + p2i(2*og + (q2 & 1));
    float* pwy = s_ys + pY(g3);

    // ---------------- initial y0 = MLP(x0) (unchanged, validated) ----------------
    if (tid < W) {
        const float4 x0 = *reinterpret_cast<const float4*>(coef_a + (size_t)b * NSTEP * D);
        const float4 w  = *reinterpret_cast<const float4*>(W0 + tid * D);
        s_h1[p1i(tid)] = softplus_f(w.x*x0.x + w.y*x0.y + w.z*x0.z + w.w*x0.w + b0[tid]);
    }
    __syncthreads();
    if (tid < W) {
        float a = b1[tid];
        #pragma unroll
        for (int blk = 0; blk < 4; ++blk)
            #pragma unroll
            for (int i = 0; i < 8; ++i) {
                float4 wv = *reinterpret_cast<const float4*>(W1 + tid * W + blk * 32 + 4 * i);
                float4 hv = *reinterpret_cast<const float4*>(s_h1 + blk * 36 + 4 * i);
                a += wv.x*hv.x + wv.y*hv.y + wv.z*hv.z + wv.w*hv.w;
            }
        s_h2[p2i(tid)] = softplus_f(a);
    }
    __syncthreads();
    if (tid < H) {
        float a = b2[tid];
        #pragma unroll
        for (int blk = 0; blk < 2; ++blk)
            #pragma unroll
            for (int i = 0; i < 16; ++i) {
                float4 wv = *reinterpret_cast<const float4*>(W2 + tid * W + blk * 64 + 4 * i);
                float4 hv = *reinterpret_cast<const float4*>(s_h2 + blk * 72 + 4 * i);
                a += wv.x*hv.x + wv.y*hv.y + wv.z*hv.z + wv.w*hv.w;
            }
        s_ys[pY(tid)] = a;
    }
    __syncthreads();

    float y = s_ys[pY(g3)];

    auto project = [&](int tslot) {
        if (tid < 64) {
            float yv = s_ys[pY(tid)];
            float p0 = yv * L0r, p1 = yv * L1r, p2 = yv * L2r;
            #pragma unroll
            for (int off = 32; off >= 1; off >>= 1) {
                p0 += __shfl_xor(p0, off);
                p1 += __shfl_xor(p1, off);
                p2 += __shfl_xor(p2, off);
            }
            if (tid == 0) {
                float* dst = out + ((size_t)b * NT + tslot) * 3;
                dst[0] = p0 + lb0; dst[1] = p1 + lb1; dst[2] = p2 + lb2;
            }
        }
    };
    project(0);

    const float* cb_pl = coef_b + (size_t)b * NSTEP * D + dsel;
    const float* cc_pl = coef_c + (size_t)b * NSTEP * D + dsel;
    const float* cd_pl = coef_d + (size_t)b * NSTEP * D + dsel;

    // ---------------- main scan: 1023 steps x 6 stages, 3 barriers/stage ----------------
    for (int t = 0; t < NSTEP; ++t) {
        const float cbd = cb_pl[(size_t)t * D];
        const float ccd = cc_pl[(size_t)t * D];
        const float cdd = cd_pl[(size_t)t * D];
        const float dtv = ts[t + 1] - ts[t];

        float k[6];

        #pragma unroll
        for (int s = 0; s < 6; ++s) {
            // ---- Phase A: L1 (64 -> 128), identical to the 7374-us kernel ----
            {
                float4 h0 = *reinterpret_cast<const float4*>(pA + 0);
                float4 h1 = *reinterpret_cast<const float4*>(pA + 4);
                float4 h2 = *reinterpret_cast<const float4*>(pA + 8);
                float4 h3 = *reinterpret_cast<const float4*>(pA + 12);
                float a1  = wA[0]*h0.x + wA[1]*h0.y + wA[2]*h0.z + wA[3]*h0.w
                          + wA[4]*h1.x + wA[5]*h1.y + wA[6]*h1.z + wA[7]*h1.w;
                float a1b = wA[8]*h2.x + wA[9]*h2.y + wA[10]*h2.z + wA[11]*h2.w
                          + wA[12]*h3.x + wA[13]*h3.y + wA[14]*h3.z + wA[15]*h3.w;
                float a1s = a1 + a1b;
                a1s += dppmv<0xB1>(a1s);
                a1s += dppmv<0x4E>(a1s);
                if (q12 == 0) *pw1 = softplus_f(a1s + g0r);
            }
            __syncthreads();

            // ---- Phase B: L2 (128 -> 128), 2 outputs per 8-lane group, 16-slice ----
            {
                float4 u0 = *reinterpret_cast<const float4*>(pB + 0);
                float4 u1 = *reinterpret_cast<const float4*>(pB + 4);
                float4 u2 = *reinterpret_cast<const float4*>(pB + 8);
                float4 u3 = *reinterpret_cast<const float4*>(pB + 12);
                float p0 = wB0[0]*u0.x + wB0[1]*u0.y + wB0[2]*u0.z + wB0[3]*u0.w
                         + wB0[4]*u1.x + wB0[5]*u1.y + wB0[6]*u1.z + wB0[7]*u1.w
                         + wB0[8]*u2.x + wB0[9]*u2.y + wB0[10]*u2.z + wB0[11]*u2.w
                         + wB0[12]*u3.x + wB0[13]*u3.y + wB0[14]*u3.z + wB0[15]*u3.w;
                float p1 = wB1[0]*u0.x + wB1[1]*u0.y + wB1[2]*u0.z + wB1[3]*u0.w
                         + wB1[4]*u1.x + wB1[5]*u1.y + wB1[6]*u1.z + wB1[7]*u1.w
                         + wB1[8]*u2.x + wB1[9]*u2.y + wB1[10]*u2.z + wB1[11]*u2.w
                         + wB1[12]*u3.x + wB1[13]*u3.y + wB1[14]*u3.z + wB1[15]*u3.w;
                // 8-lane all-reduce: quad sums (xor1,xor2) then cross-quad via
                // half-mirror (valid: values quad-uniform after xor1+xor2).
                p0 += dppmv<0xB1>(p0); p1 += dppmv<0xB1>(p1);
                p0 += dppmv<0x4E>(p0); p1 += dppmv<0x4E>(p1);
                p0 += dppmv<0x141>(p0); p1 += dppmv<0x141>(p1);
                float spv = softplus_f(((q2 & 1) ? p1 : p0) + g1s);
                if (q2 < 2) *pw2 = spv;
            }
            __syncthreads();

            // ---- Phase C: L3 (128 -> 256), 2 outputs per quad + einsum + RK ----
            {
                float p0 = 0.f, p1 = 0.f;
                #pragma unroll
                for (int m = 0; m < 8; ++m) {
                    float4 u = *reinterpret_cast<const float4*>(pC + 4*m);
                    p0 += wC0[4*m+0]*u.x + wC0[4*m+1]*u.y + wC0[4*m+2]*u.z + wC0[4*m+3]*u.w;
                    p1 += wC1[4*m+0]*u.x + wC1[4*m+1]*u.y + wC1[4*m+2]*u.z + wC1[4*m+3]*u.w;
                }
                // quad all-reduce -> every lane holds both output dots
                p0 += dppmv<0xB1>(p0); p1 += dppmv<0xB1>(p1);
                p0 += dppmv<0x4E>(p0); p1 += dppmv<0x4E>(p1);
                const float ft = tanh_f(((tid & 1) ? p1 : p0) + g2s);

                const float frac = cFR[s] * dtv;
                const float dxd  = fmaf(frac, fmaf(3.0f * frac, cdd, 2.0f * ccd), cbd);
                // lanes of the 8-group hold (f,dx) pairs for d = {0,1,0,1,2,3,2,3}
                // (grp parity picks d-pair, tid&1 picks within pair) -> each d twice.
                // Sum over 8 lanes = 2*k[h]; fold the 0.5 in before reducing.
                float pk = ft * dxd * 0.5f;
                pk += dppmv<0xB1>(pk);
                pk += dppmv<0x4E>(pk);
                pk += dppmv<0x141>(pk);      // cross-quad (quad-uniform) -> k on all 8 lanes
                k[s] = pk;

                float ysn;
                if (s < 5) {
                    float acc = 0.f;
                    #pragma unroll
                    for (int i = 0; i <= s; ++i) acc = fmaf(cAT[s+1][i], k[i], acc);
                    ysn = fmaf(dtv, acc, y);
                } else {
                    float acc = 0.f;
                    #pragma unroll
                    for (int i = 0; i < 6; ++i) acc = fmaf(cBW[i], k[i], acc);
                    ysn = fmaf(dtv, acc, y);
                }
                if ((tid & 7) == 0) *pwy = ysn;
            }
            __syncthreads();
        }

        y = *pwy;          // single source of truth: writer lane's value
        project(t + 1);    // wave0 projects while other waves start next phase A
    }
}

} // namespace

extern "C" void kernel_launch(void* const* d_in, const int* in_sizes, int n_in,
                              void* d_out, int out_size, void* d_ws, size_t ws_size,
                              hipStream_t stream) {
    const float* ts     = (const float*)d_in[0];
    const float* coef_d = (const float*)d_in[1];
    const float* coef_c = (const float*)d_in[2];
    const float* coef_b = (const float*)d_in[3];
    const float* coef_a = (const float*)d_in[4];
    const float* W0 = (const float*)d_in[5];
    const float* b0 = (const float*)d_in[6];
    const float* W1 = (const float*)d_in[7];
    const float* b1 = (const float*)d_in[8];
    const float* W2 = (const float*)d_in[9];
    const float* b2 = (const float*)d_in[10];
    const float* F0 = (const float*)d_in[11];
    const float* g0 = (const float*)d_in[12];
    const float* F1 = (const float*)d_in[13];
    const float* g1 = (const float*)d_in[14];
    const float* F2 = (const float*)d_in[15];
    const float* g2 = (const float*)d_in[16];
    const float* Lm = (const float*)d_in[17];
    const float* lb = (const float*)d_in[18];
    float* out = (float*)d_out;

    hipLaunchKernelGGL(cde_kernel, dim3(NB), dim3(512), 0, stream,
                       ts, coef_d, coef_c, coef_b, coef_a,
                       W0, b0, W1, b1, W2, b2,
                       F0, g0, F1, g1, F2, g2, Lm, lb, out);
}